// Round 10
// baseline (214.932 us; speedup 1.0000x reference)
//
#include <hip/hip_runtime.h>

#define NPOS 576      // B*oH*oW
#define KTOT 144      // KH*KW*IC
#define NOC 32
#define NP 16
#define OCP 512
#define EPSF 1e-7f
#define LOG2PIF 1.83787706640934548356f

// Round 10: d_out is FLOAT32 (bound-violation forensics + out_npz size).
// Semantics: the shown JAX reference, faithfully, in f32.
__global__ __launch_bounds__(512) void em_routing(
    const float* __restrict__ Vf, const float* __restrict__ Af,
    const float* __restrict__ Bup, const float* __restrict__ Bap,
    float* __restrict__ out)
{
  const int pos = blockIdx.x;           // 0..575
  const int t   = (int)threadIdx.x;     // 0..511
  const int oc  = t >> 4;
  const int p   = t & 15;

  __shared__ float sRw[KTOT][NOC];      // Rw weights; reused as logit buffer
  __shared__ float sA[KTOT];
  __shared__ float sMu[OCP];
  __shared__ float sC0[OCP];
  __shared__ float sLog[OCP];
  __shared__ float sX[NOC];
  __shared__ float sBase[NOC];

  const size_t vbase = (size_t)pos * (KTOT * OCP);
  const float Bu = Bup[oc];
  const float Ba = Bap[oc];

  if (t < KTOT) sA[t] = Af[pos * KTOT + t];
  __syncthreads();

  // R init = 1/32  =>  Rw = a/32
  for (int idx = t; idx < KTOT * NOC; idx += 512)
    sRw[idx >> 5][idx & 31] = sA[idx >> 5] * (1.0f / 32.0f);
  __syncthreads();

  float mu = 0.f, sig = 1.f, aout = 0.5f;

  for (int it = 0; it < 3; ++it) {
    const float lam = (it == 0) ? 5e-4f : (it == 1) ? 9.75e-4f : 1.42625e-3f;

    // ---- pass A1: denom and mu (normalized) ----
    float s0 = 0.f, s1 = 0.f;
    for (int k = 0; k < KTOT; ++k) {
      float w = sRw[k][oc];
      float v = Vf[vbase + k * OCP + t];
      s0 += w;
      s1 += w * v;
    }
    const float denom = s0;
    const float inv   = 1.0f / (denom + EPSF);
    mu = s1 * inv;

    // ---- pass A2: sigma_sqr = sum(Rw*(V-mu)^2) * inv (shown semantics) ----
    float s2 = 0.f;
    for (int k = 0; k < KTOT; ++k) {
      float w = sRw[k][oc];
      float v = Vf[vbase + k * OCP + t];
      float d = v - mu;
      s2 += w * d * d;
    }
    sig = s2 * inv;

    // ---- p-group reduction of log(sigma) via LDS ----
    sLog[t] = logf(sig);
    __syncthreads();                          // B1
    float L = 0.f;
    for (int q = 0; q < NP; ++q) L += sLog[oc * NP + q];

    // x = lam*(Ba - denom*(16*Bu + 0.5*L))
    const float x = lam * (Ba - denom * (16.0f * Bu + 0.5f * L));
    if (p == 0) sX[oc] = x;
    __syncthreads();                          // B2
    float ss = 0.f;
    for (int j = 0; j < NOC; ++j) ss += sX[j] * sX[j];
    const float nrm = fmaxf(sqrtf(ss), 1e-12f);
    aout = 1.0f / (1.0f + expf(-sX[oc] / nrm));

    if (it == 2) break;                       // final E-step dead in shown code

    // ---- stage per-(oc,p) stats for logit pass ----
    sMu[t] = mu;
    sC0[t] = 1.0f / (2.0f * sig + EPSF);
    if (p == 0)
      sBase[oc] = logf(aout) + (-0.5f * (16.0f * LOG2PIF + L) + EPSF);
    __syncthreads();                          // B3

    // ---- pass B: logits[k][oc] = base[oc] - sum_p (V-mu)^2 * c0 ----
    for (int idx = t; idx < KTOT * NOC; idx += 512) {
      const int k = idx >> 5, o = idx & 31;
      float s = 0.f;
      for (int q = 0; q < NP; ++q) {
        float v = Vf[vbase + k * OCP + o * NP + q];
        float d = v - sMu[o * NP + q];
        s += d * d * sC0[o * NP + q];
      }
      sRw[k][o] = sBase[o] - s;
    }
    __syncthreads();                          // B4

    // ---- softmax over oc per row k, then fold in a[k]: Rw = softmax * a ----
    if (t < KTOT) {
      float mx = -3.4e38f;
      for (int j = 0; j < NOC; ++j) mx = fmaxf(mx, sRw[t][j]);
      float sum = 0.f;
      for (int j = 0; j < NOC; ++j) sum += expf(sRw[t][j] - mx);
      const float fac = sA[t] / sum;
      for (int j = 0; j < NOC; ++j) sRw[t][j] = expf(sRw[t][j] - mx) * fac;
    }
    __syncthreads();                          // B5
  }

  // ---- outputs (FLOAT32): mu [0:294912] | a_out [294912:313344] |
  //                         sigma [313344:608256] ----
  const size_t base_mu = (size_t)pos * OCP + t;
  out[base_mu]           = mu;
  out[313344u + base_mu] = sig;
  if (p == 0) out[294912u + (size_t)pos * NOC + oc] = aout;
}

extern "C" void kernel_launch(void* const* d_in, const int* in_sizes, int n_in,
                              void* d_out, int out_size, void* d_ws, size_t ws_size,
                              hipStream_t stream) {
  em_routing<<<NPOS, 512, 0, stream>>>((const float*)d_in[0], (const float*)d_in[1],
                                       (const float*)d_in[2], (const float*)d_in[3],
                                       (float*)d_out);
}